// Round 18
// baseline (238.574 us; speedup 1.0000x reference)
//
#include <hip/hip_runtime.h>

// C3-style layer via MFMA implicit GEMM, R17 = R16 + (a) deferred
// double-buffered commit: loads issued at phase t are vmcnt-waited and
// committed at END of phase t+1 (full-phase HBM latency cover; R16 waited
// within the issuing phase, ~600cy < ~900cy miss latency), and (b)
// s_setprio(1) around the MFMA cluster (phase-split role diversity ->
// scheduler arbitration pays, T5).  Ring slot timing re-derived: commit
// slots (8t+20..27)&31 disjoint from epoch t+1 reads, barrier-ordered
// before first read at t+2; old content last read at t-2.  Everything else
// verbatim R16 (slot-major LDS, XCD slab remap, lgkm-only ring barriers).
// x[32,6,512,512] f32 -> out[32,16,508,508] f32 (5x5 VALID conv; sparse
// oc<-ic connectivity via zero weights in dense [16,6,5,5] kernel).

#define OW 508
#define BX 64     // output px per block; 2 strips x 32
#define TC 68     // staged columns = BX + 4
#define RM 31     // ring mask (32 slots)

typedef _Float16 h8 __attribute__((ext_vector_type(8)));
typedef _Float16 h2 __attribute__((ext_vector_type(2)));
typedef float f32x16 __attribute__((ext_vector_type(16)));

__device__ __constant__ int d_CH3[6][3] = {
    {0,1,2},{1,2,3},{2,3,4},{3,4,5},{0,4,5},{0,1,5}};
__device__ __constant__ int d_CH4[9][4] = {
    {0,1,2,3},{1,2,3,4},{2,3,4,5},{0,3,4,5},{0,1,4,5},
    {0,1,2,5},{0,1,3,4},{1,2,4,5},{0,2,3,5}};

// ws: bias f32[16] | AF ushort[15*64*8]
// AF[((kx*3+ch)*64 + lane)*8 + e]: A-frag: oc=lane&15, dy=(lane>>4)&1,
// rr=lane>>5, ky=ch*2+rr-dy; value W[oc][e][ky][kx] or 0.  (verified R6)
__global__ void prep_weights(const float* __restrict__ w3, const float* __restrict__ b3,
                             const float* __restrict__ w4, const float* __restrict__ b4,
                             const float* __restrict__ w6, const float* __restrict__ b6,
                             float* __restrict__ bias, unsigned short* __restrict__ AF) {
    __shared__ float Wfull[16 * 6 * 25];   // dense [oc][ic][tap]
    const int tid = threadIdx.x;
    for (int i = tid; i < 16 * 6 * 25; i += 256) Wfull[i] = 0.f;
    __syncthreads();
    for (int i = tid; i < 6 * 3 * 25; i += 256) {
        int oc = i / 75, r = i % 75, c = r / 25, t = r % 25;
        Wfull[(oc * 6 + d_CH3[oc][c]) * 25 + t] = w3[i];
    }
    for (int i = tid; i < 9 * 4 * 25; i += 256) {
        int o = i / 100, r = i % 100, c = r / 25, t = r % 25;
        Wfull[((6 + o) * 6 + d_CH4[o][c]) * 25 + t] = w4[i];
    }
    for (int i = tid; i < 6 * 25; i += 256) Wfull[15 * 150 + i] = w6[i];
    __syncthreads();
    for (int i = tid; i < 15 * 64 * 8; i += 256) {
        int e = i & 7, lane = (i >> 3) & 63, q = i >> 9;   // q = kx*3+ch
        int kx = q / 3, ch = q % 3;
        int oc = lane & 15, dy = (lane >> 4) & 1, rr = lane >> 5;
        int ky = ch * 2 + rr - dy;
        float w = 0.f;
        if (e < 6 && ky >= 0 && ky <= 4) w = Wfull[(oc * 6 + e) * 25 + ky * 5 + kx];
        _Float16 hw = (_Float16)w;
        AF[i] = __builtin_bit_cast(unsigned short, hw);
    }
    if (tid < 6)        bias[tid] = b3[tid];
    else if (tid < 15)  bias[tid] = b4[tid - 6];
    else if (tid == 15) bias[tid] = b6[0];
}

__device__ __forceinline__ void pack2(const float2 (&v)[6], uint4& wA, uint4& wB) {
    h2 a0; a0.x = (_Float16)v[0].x; a0.y = (_Float16)v[1].x;
    h2 a1; a1.x = (_Float16)v[2].x; a1.y = (_Float16)v[3].x;
    h2 a2; a2.x = (_Float16)v[4].x; a2.y = (_Float16)v[5].x;
    h2 b0; b0.x = (_Float16)v[0].y; b0.y = (_Float16)v[1].y;
    h2 b1; b1.x = (_Float16)v[2].y; b1.y = (_Float16)v[3].y;
    h2 b2; b2.x = (_Float16)v[4].y; b2.y = (_Float16)v[5].y;
    wA.x = __builtin_bit_cast(unsigned int, a0);
    wA.y = __builtin_bit_cast(unsigned int, a1);
    wA.z = __builtin_bit_cast(unsigned int, a2);
    wA.w = 0u;
    wB.x = __builtin_bit_cast(unsigned int, b0);
    wB.y = __builtin_bit_cast(unsigned int, b1);
    wB.z = __builtin_bit_cast(unsigned int, b2);
    wB.w = 0u;
}

// Ring barrier: order ds_writes (lgkmcnt) across waves WITHOUT draining
// in-flight global stores (vmcnt) like __syncthreads does.
__device__ __forceinline__ void ring_barrier() {
    asm volatile("s_waitcnt lgkmcnt(0)" ::: "memory");
    __builtin_amdgcn_s_barrier();
    __builtin_amdgcn_sched_barrier(0);   // rule #18: nothing crosses
}

__global__ __launch_bounds__(512, 4) void conv_mfma(
        const float* __restrict__ x, const unsigned short* __restrict__ AF,
        const float* __restrict__ bias, float* __restrict__ out) {
    __shared__ uint4 T4[32 * TC];   // 34816 B, slot-major: block = slot*TC + col

    const int tid = threadIdx.x;

    // XCD-coherent remap (bijective on 2048): xcd = id&7 (round-robin dispatch)
    const int id  = blockIdx.x + 8 * (blockIdx.y + 8 * blockIdx.z);
    const int xcd = id & 7;
    const int pos = id >> 3;                 // 0..255
    const int bz  = xcd * 4 + (pos >> 6);
    const int by  = (pos >> 3) & 7;
    const int bx  = pos & 7;

    const int gx0 = bx * BX;
    const int Y0  = by * 64;                 // output rows Y0 .. Y0+63
    const float* xb = x + (size_t)bz * 6 * 512 * 512;

    const int lane = tid & 63;
    const int h = lane >> 5;                 // K-half (verified R6 mapping)

    h8 afr[15];
    #pragma unroll
    for (int q = 0; q < 15; ++q)
        afr[q] = *reinterpret_cast<const h8*>(AF + (q * 64 + lane) * 8);

    float bv[8];
    #pragma unroll
    for (int r8 = 0; r8 < 8; ++r8)
        bv[r8] = bias[(r8 & 3) + 8 * (r8 >> 2) + 4 * h];

    // staging thread geometry (fixed across phases)
    const bool ldr = (tid < 272);
    const int scp = tid % 34, srr = tid / 34;       // valid when ldr
    const int sc  = 2 * scp;
    const int sgx = gx0 + sc;

    // ---- prologue: stage input rows Y0..Y0+19 into slots 0..19 (Y0%32==0;
    //      Y0<=448 so gy<=467<512 always)
    #pragma unroll
    for (int k = 0; k < 2; ++k) {
        int idx = tid + k * 512;
        if (idx < 680) {
            int cp = idx % 34, rr = idx / 34;
            int c = 2 * cp, gx = gx0 + c, gy = Y0 + rr;
            float2 v[6];
            #pragma unroll
            for (int ic = 0; ic < 6; ++ic) v[ic] = (float2){0.f, 0.f};
            if (gx < 512) {
                const float* rp = xb + (size_t)gy * 512 + gx;
                #pragma unroll
                for (int ic = 0; ic < 6; ++ic)
                    v[ic] = *(const float2*)(rp + (size_t)ic * 262144);
            }
            uint4 wA, wB;
            pack2(v, wA, wB);
            T4[rr * TC + c]     = wA;
            T4[rr * TC + c + 1] = wB;
        }
    }
    ring_barrier();

    const int wv = tid >> 6;
    const int s  = wv & 1;                   // px strip
    const int dh = (wv >> 1) & 1;            // d half
    const int ch = wv >> 2;                  // chain
    const int colb = s * 32 + (lane & 31);
    const int px = gx0 + colb;
    const bool pxok = (px < OW);
    const size_t cs = (size_t)OW * OW;
    float* ob = out + ((size_t)bz * 16 + 4 * h) * cs + px;

    float2 vaA[6], vaB[6];
    int slA = -1, slB = -1;

    // ---- macros for the phase body pieces (named buffers; rule #20) ----
#define ISSUE(va, sl, t)                                                     \
    {                                                                        \
        sl = -1;                                                             \
        if ((t) < 6 && ldr) {                                                \
            int gy = Y0 + 8 * (t) + 20 + srr;                                \
            _Pragma("unroll")                                                \
            for (int ic = 0; ic < 6; ++ic) va[ic] = (float2){0.f, 0.f};      \
            if (gy < 512 && sgx < 512) {                                     \
                const float* rp = xb + (size_t)gy * 512 + sgx;               \
                _Pragma("unroll")                                            \
                for (int ic = 0; ic < 6; ++ic)                               \
                    va[ic] = *(const float2*)(rp + (size_t)ic * 262144);     \
            }                                                                \
            sl = gy & RM;                                                    \
        }                                                                    \
    }

#define COMPUTE_STORE(t)                                                     \
    {                                                                        \
        const int sb = 8 * (t) + 4 * dh + 2 * ch + h;                        \
        const int s0 = sb & RM, s1 = (sb + 2) & RM, s2 = (sb + 4) & RM;      \
        f32x16 acc;                                                          \
        _Pragma("unroll")                                                    \
        for (int r = 0; r < 16; ++r) acc[r] = 0.f;                           \
        __builtin_amdgcn_s_setprio(1);                                       \
        _Pragma("unroll")                                                    \
        for (int kx = 0; kx < 5; ++kx) {                                     \
            h8 b0 = *reinterpret_cast<const h8*>(&T4[s0 * TC + colb + kx]);  \
            h8 b1 = *reinterpret_cast<const h8*>(&T4[s1 * TC + colb + kx]);  \
            h8 b2 = *reinterpret_cast<const h8*>(&T4[s2 * TC + colb + kx]);  \
            acc = __builtin_amdgcn_mfma_f32_32x32x16_f16(afr[kx * 3 + 0], b0, acc, 0, 0, 0); \
            acc = __builtin_amdgcn_mfma_f32_32x32x16_f16(afr[kx * 3 + 1], b1, acc, 0, 0, 0); \
            acc = __builtin_amdgcn_mfma_f32_32x32x16_f16(afr[kx * 3 + 2], b2, acc, 0, 0, 0); \
        }                                                                    \
        __builtin_amdgcn_s_setprio(0);                                       \
        const int oyb = Y0 + 8 * (t) + 4 * dh + 2 * ch;                      \
        _Pragma("unroll")                                                    \
        for (int dy = 0; dy < 2; ++dy) {                                     \
            const int oy = oyb + dy;                                         \
            if (oy < OW && pxok) {                                           \
                _Pragma("unroll")                                            \
                for (int r8 = 0; r8 < 8; ++r8) {                             \
                    const int ocb = (r8 & 3) + 8 * (r8 >> 2);                \
                    ob[(size_t)ocb * cs + (size_t)oy * OW] = acc[dy * 8 + r8] + bv[r8]; \
                }                                                            \
            }                                                                \
        }                                                                    \
    }

#define COMMIT(va, sl)                                                       \
    {                                                                        \
        if (sl >= 0) {                                                       \
            uint4 wA, wB;                                                    \
            pack2(va, wA, wB);                                               \
            T4[sl * TC + sc]     = wA;                                       \
            T4[sl * TC + sc + 1] = wB;                                       \
        }                                                                    \
    }

    #pragma unroll 1
    for (int it = 0; it < 4; ++it) {
        const int tE = 2 * it;          // even phase
        const int tO = tE + 1;          // odd phase

        // -- even phase: issue->vaA; commit vaB (issued tE-1)
        ISSUE(vaA, slA, tE);
        COMPUTE_STORE(tE);
        if (tE >= 1) { COMMIT(vaB, slB); }
        if (tE >= 1) ring_barrier(); else { ring_barrier(); }  // reads at tO ordered

        // -- odd phase: issue->vaB; commit vaA (issued tE)
        ISSUE(vaB, slB, tO);
        COMPUTE_STORE(tO);
        if (tE < 6) { COMMIT(vaA, slA); }
        if (tO < 7) ring_barrier();
    }
#undef ISSUE
#undef COMPUTE_STORE
#undef COMMIT
}

extern "C" void kernel_launch(void* const* d_in, const int* in_sizes, int n_in,
                              void* d_out, int out_size, void* d_ws, size_t ws_size,
                              hipStream_t stream) {
    const float* x  = (const float*)d_in[0];
    const float* w3 = (const float*)d_in[1];
    const float* b3 = (const float*)d_in[2];
    const float* w4 = (const float*)d_in[3];
    const float* b4 = (const float*)d_in[4];
    const float* w6 = (const float*)d_in[5];
    const float* b6 = (const float*)d_in[6];
    float* out = (float*)d_out;

    float* bias        = (float*)d_ws;                    // 16 f32
    unsigned short* AF = (unsigned short*)(bias + 16);    // 7680 u16

    prep_weights<<<1, 256, 0, stream>>>(w3, b3, w4, b4, w6, b6, bias, AF);

    dim3 grid(8, 8, 32);   // remapped in-kernel to XCD-coherent slabs
    conv_mfma<<<grid, 512, 0, stream>>>(x, AF, bias, out);
}

// Round 19
// 221.072 us; speedup vs baseline: 1.0792x; 1.0792x over previous
//
#include <hip/hip_runtime.h>

// C3-style layer via MFMA implicit GEMM — FINAL (R18 = R16 verbatim revert;
// R17's deferred-commit + setprio experiment regressed 221->239 and is
// dropped).  64-row y-walk ring pipeline: 8 phases/block, prefetch 2 phases
// ahead, slot-major LDS (conflict-free b128 reads), XCD-coherent batch-slab
// remap, lgkm-only ring barriers (stores stay in flight).
// x[32,6,512,512] f32 -> out[32,16,508,508] f32 (5x5 VALID conv; sparse
// oc<-ic connectivity via zero weights in dense [16,6,5,5] kernel).

#define OW 508
#define BX 64     // output px per block; 2 strips x 32
#define TC 68     // staged columns = BX + 4
#define RM 31     // ring mask (32 slots)

typedef _Float16 h8 __attribute__((ext_vector_type(8)));
typedef _Float16 h2 __attribute__((ext_vector_type(2)));
typedef float f32x16 __attribute__((ext_vector_type(16)));

__device__ __constant__ int d_CH3[6][3] = {
    {0,1,2},{1,2,3},{2,3,4},{3,4,5},{0,4,5},{0,1,5}};
__device__ __constant__ int d_CH4[9][4] = {
    {0,1,2,3},{1,2,3,4},{2,3,4,5},{0,3,4,5},{0,1,4,5},
    {0,1,2,5},{0,1,3,4},{1,2,4,5},{0,2,3,5}};

// ws: bias f32[16] | AF ushort[15*64*8]
// AF[((kx*3+ch)*64 + lane)*8 + e]: A-frag: oc=lane&15, dy=(lane>>4)&1,
// rr=lane>>5, ky=ch*2+rr-dy; value W[oc][e][ky][kx] or 0.  (verified R6)
__global__ void prep_weights(const float* __restrict__ w3, const float* __restrict__ b3,
                             const float* __restrict__ w4, const float* __restrict__ b4,
                             const float* __restrict__ w6, const float* __restrict__ b6,
                             float* __restrict__ bias, unsigned short* __restrict__ AF) {
    __shared__ float Wfull[16 * 6 * 25];   // dense [oc][ic][tap]
    const int tid = threadIdx.x;
    for (int i = tid; i < 16 * 6 * 25; i += 256) Wfull[i] = 0.f;
    __syncthreads();
    for (int i = tid; i < 6 * 3 * 25; i += 256) {
        int oc = i / 75, r = i % 75, c = r / 25, t = r % 25;
        Wfull[(oc * 6 + d_CH3[oc][c]) * 25 + t] = w3[i];
    }
    for (int i = tid; i < 9 * 4 * 25; i += 256) {
        int o = i / 100, r = i % 100, c = r / 25, t = r % 25;
        Wfull[((6 + o) * 6 + d_CH4[o][c]) * 25 + t] = w4[i];
    }
    for (int i = tid; i < 6 * 25; i += 256) Wfull[15 * 150 + i] = w6[i];
    __syncthreads();
    for (int i = tid; i < 15 * 64 * 8; i += 256) {
        int e = i & 7, lane = (i >> 3) & 63, q = i >> 9;   // q = kx*3+ch
        int kx = q / 3, ch = q % 3;
        int oc = lane & 15, dy = (lane >> 4) & 1, rr = lane >> 5;
        int ky = ch * 2 + rr - dy;
        float w = 0.f;
        if (e < 6 && ky >= 0 && ky <= 4) w = Wfull[(oc * 6 + e) * 25 + ky * 5 + kx];
        _Float16 hw = (_Float16)w;
        AF[i] = __builtin_bit_cast(unsigned short, hw);
    }
    if (tid < 6)        bias[tid] = b3[tid];
    else if (tid < 15)  bias[tid] = b4[tid - 6];
    else if (tid == 15) bias[tid] = b6[0];
}

__device__ __forceinline__ void pack2(const float2 (&v)[6], uint4& wA, uint4& wB) {
    h2 a0; a0.x = (_Float16)v[0].x; a0.y = (_Float16)v[1].x;
    h2 a1; a1.x = (_Float16)v[2].x; a1.y = (_Float16)v[3].x;
    h2 a2; a2.x = (_Float16)v[4].x; a2.y = (_Float16)v[5].x;
    h2 b0; b0.x = (_Float16)v[0].y; b0.y = (_Float16)v[1].y;
    h2 b1; b1.x = (_Float16)v[2].y; b1.y = (_Float16)v[3].y;
    h2 b2; b2.x = (_Float16)v[4].y; b2.y = (_Float16)v[5].y;
    wA.x = __builtin_bit_cast(unsigned int, a0);
    wA.y = __builtin_bit_cast(unsigned int, a1);
    wA.z = __builtin_bit_cast(unsigned int, a2);
    wA.w = 0u;
    wB.x = __builtin_bit_cast(unsigned int, b0);
    wB.y = __builtin_bit_cast(unsigned int, b1);
    wB.z = __builtin_bit_cast(unsigned int, b2);
    wB.w = 0u;
}

// Ring barrier: order ds_writes (lgkmcnt) across waves WITHOUT draining
// in-flight global stores (vmcnt) like __syncthreads does.
__device__ __forceinline__ void ring_barrier() {
    asm volatile("s_waitcnt lgkmcnt(0)" ::: "memory");
    __builtin_amdgcn_s_barrier();
    __builtin_amdgcn_sched_barrier(0);   // rule #18: nothing crosses
}

__global__ __launch_bounds__(512, 4) void conv_mfma(
        const float* __restrict__ x, const unsigned short* __restrict__ AF,
        const float* __restrict__ bias, float* __restrict__ out) {
    __shared__ uint4 T4[32 * TC];   // 34816 B, slot-major: block = slot*TC + col

    const int tid = threadIdx.x;

    // XCD-coherent remap (bijective on 2048): xcd = id&7 (round-robin dispatch)
    const int id  = blockIdx.x + 8 * (blockIdx.y + 8 * blockIdx.z);
    const int xcd = id & 7;
    const int pos = id >> 3;                 // 0..255
    const int bz  = xcd * 4 + (pos >> 6);
    const int by  = (pos >> 3) & 7;
    const int bx  = pos & 7;

    const int gx0 = bx * BX;
    const int Y0  = by * 64;                 // output rows Y0 .. Y0+63
    const float* xb = x + (size_t)bz * 6 * 512 * 512;

    const int lane = tid & 63;
    const int h = lane >> 5;                 // K-half (verified R6 mapping)

    h8 afr[15];
    #pragma unroll
    for (int q = 0; q < 15; ++q)
        afr[q] = *reinterpret_cast<const h8*>(AF + (q * 64 + lane) * 8);

    float bv[8];
    #pragma unroll
    for (int r8 = 0; r8 < 8; ++r8)
        bv[r8] = bias[(r8 & 3) + 8 * (r8 >> 2) + 4 * h];

    // ---- prologue: stage input rows Y0..Y0+19 into slots 0..19 (Y0%32==0;
    //      Y0<=448 so gy<=467<512 always)
    #pragma unroll
    for (int k = 0; k < 2; ++k) {
        int idx = tid + k * 512;
        if (idx < 680) {
            int cp = idx % 34, rr = idx / 34;
            int c = 2 * cp, gx = gx0 + c, gy = Y0 + rr;
            float2 v[6];
            #pragma unroll
            for (int ic = 0; ic < 6; ++ic) v[ic] = (float2){0.f, 0.f};
            if (gx < 512) {
                const float* rp = xb + (size_t)gy * 512 + gx;
                #pragma unroll
                for (int ic = 0; ic < 6; ++ic)
                    v[ic] = *(const float2*)(rp + (size_t)ic * 262144);
            }
            uint4 wA, wB;
            pack2(v, wA, wB);
            T4[rr * TC + c]     = wA;
            T4[rr * TC + c + 1] = wB;
        }
    }
    ring_barrier();

    const int wv = tid >> 6;
    const int s  = wv & 1;                   // px strip
    const int dh = (wv >> 1) & 1;            // d half (rows 4*dh..4*dh+3 of phase)
    const int ch = wv >> 2;                  // chain (rows +2*ch)
    const int colb = s * 32 + (lane & 31);
    const int px = gx0 + colb;
    const bool pxok = (px < OW);
    const size_t cs = (size_t)OW * OW;
    float* ob = out + ((size_t)bz * 16 + 4 * h) * cs + px;

    #pragma unroll 1
    for (int t = 0; t < 8; ++t) {
        // -- issue loads for input rows Y0+8t+20..+27 (consumed at phase t+2;
        //    rows exist only for t<6)
        float2 va[6];
        int wslot = -1, wcol = 0;
        if (t < 6 && tid < 272) {
            int cp = tid % 34, rr = tid / 34;
            int c = 2 * cp, gx = gx0 + c, gy = Y0 + 8 * t + 20 + rr;
            #pragma unroll
            for (int ic = 0; ic < 6; ++ic) va[ic] = (float2){0.f, 0.f};
            if (gy < 512 && gx < 512) {
                const float* rp = xb + (size_t)gy * 512 + gx;
                #pragma unroll
                for (int ic = 0; ic < 6; ++ic)
                    va[ic] = *(const float2*)(rp + (size_t)ic * 262144);
            }
            wslot = gy & RM;   // wrap rows >=512 commit zeros; they feed only
            wcol = c;          // oy>=OW-masked outputs (derived safe)
        }

        // -- compute: one chain (15 ds_read_b128 + 15 MFMA)
        const int sb = 8 * t + 4 * dh + 2 * ch + h;      // window-row offset
        const int s0 = sb & RM, s1 = (sb + 2) & RM, s2 = (sb + 4) & RM;
        f32x16 acc;
        #pragma unroll
        for (int r = 0; r < 16; ++r) acc[r] = 0.f;
        #pragma unroll
        for (int kx = 0; kx < 5; ++kx) {
            h8 b0 = *reinterpret_cast<const h8*>(&T4[s0 * TC + colb + kx]);
            h8 b1 = *reinterpret_cast<const h8*>(&T4[s1 * TC + colb + kx]);
            h8 b2 = *reinterpret_cast<const h8*>(&T4[s2 * TC + colb + kx]);
            acc = __builtin_amdgcn_mfma_f32_32x32x16_f16(afr[kx * 3 + 0], b0, acc, 0, 0, 0);
            acc = __builtin_amdgcn_mfma_f32_32x32x16_f16(afr[kx * 3 + 1], b1, acc, 0, 0, 0);
            acc = __builtin_amdgcn_mfma_f32_32x32x16_f16(afr[kx * 3 + 2], b2, acc, 0, 0, 0);
        }

        // -- stores (bias folded; stores stay in flight across ring_barrier)
        const int oyb = Y0 + 8 * t + 4 * dh + 2 * ch;
        #pragma unroll
        for (int dy = 0; dy < 2; ++dy) {
            const int oy = oyb + dy;
            if (oy < OW && pxok) {
                #pragma unroll
                for (int r8 = 0; r8 < 8; ++r8) {
                    const int ocb = (r8 & 3) + 8 * (r8 >> 2);
                    ob[(size_t)ocb * cs + (size_t)oy * OW] = acc[dy * 8 + r8] + bv[r8];
                }
            }
        }

        // -- commit staged rows + ring barrier (t<6; commit slots disjoint
        //    from all reads until phase t+2 -- re-derived for 8 phases)
        if (t < 6) {
            if (wslot >= 0) {
                uint4 wA, wB;
                pack2(va, wA, wB);
                T4[wslot * TC + wcol]     = wA;
                T4[wslot * TC + wcol + 1] = wB;
            }
            ring_barrier();
        }
    }
}

extern "C" void kernel_launch(void* const* d_in, const int* in_sizes, int n_in,
                              void* d_out, int out_size, void* d_ws, size_t ws_size,
                              hipStream_t stream) {
    const float* x  = (const float*)d_in[0];
    const float* w3 = (const float*)d_in[1];
    const float* b3 = (const float*)d_in[2];
    const float* w4 = (const float*)d_in[3];
    const float* b4 = (const float*)d_in[4];
    const float* w6 = (const float*)d_in[5];
    const float* b6 = (const float*)d_in[6];
    float* out = (float*)d_out;

    float* bias        = (float*)d_ws;                    // 16 f32
    unsigned short* AF = (unsigned short*)(bias + 16);    // 7680 u16

    prep_weights<<<1, 256, 0, stream>>>(w3, b3, w4, b4, w6, b6, bias, AF);

    dim3 grid(8, 8, 32);   // remapped in-kernel to XCD-coherent slabs
    conv_mfma<<<grid, 512, 0, stream>>>(x, AF, bias, out);
}